// Round 6
// baseline (10384.353 us; speedup 1.0000x reference)
//
#include <hip/hip_runtime.h>
#include <math.h>

constexpr int kB  = 128;
constexpr int kT  = 1024;
constexpr int kD  = 32;
constexpr int kH  = 64;
constexpr int kW  = 128;
constexpr int kC  = kD + 1;    // 33
constexpr int kO  = kH * kC;   // 2112
constexpr int kIN = kH + 1;    // 65
constexpr int BLOCK = 1024;    // 16 waves

// ---- int16 workspace layout (u32 units) ----
constexpr int WS_W2  = 0;            // 135168 u32 (2112 rows * 64 words), tiled
constexpr int WS_W1  = 135168;       // 8192 u32
constexpr int WS_W0  = 143360;       // 4224 u32
constexpr int WS_SC2 = 147584;       // 2112 f32 row scales
constexpr int WS_SC1 = 149696;       // 128
constexpr int WS_SC0 = 149824;       // 128
constexpr int WS_TOT = 149952;       // u32 -> 599,808 bytes (mono path)
// split-path extension: per-batch yhat exchange buffers + flags
constexpr int WS_XB   = 149952;      // float[128][2][64] = 16384 u32
constexpr int WS_FLAG = 166336;      // u32[128][2] = 256
constexpr int WS_TOT2 = 166592;      // u32 -> 666,368 bytes

__device__ __forceinline__ float fast_sigmoid(float x) { return 1.0f / (1.0f + __expf(-x)); }
__device__ __forceinline__ float lipswish_f(float x)   { return 0.909f * x * fast_sigmoid(x); }
__device__ __forceinline__ float fast_tanh(float x) {
    float ax = fabsf(x);
    float e  = __expf(2.0f * ax);
    float r  = 1.0f - 2.0f / (e + 1.0f);
    return copysignf(r, x);
}
__device__ __forceinline__ float dot4(float4 a, float4 b) {
    return a.x * b.x + a.y * b.y + a.z * b.z + a.w * b.w;
}
__device__ __forceinline__ float fma2i(unsigned u, float z0, float z1, float acc) {
    int lo = (int)(short)(u & 0xffffu);
    int hi = ((int)u) >> 16;
    acc += (float)lo * z0 + (float)hi * z1;
    return acc;
}
__device__ __forceinline__ float fma8i(uint4 u, float4 zl, float4 zh, float acc) {
    acc = fma2i(u.x, zl.x, zl.y, acc);
    acc = fma2i(u.y, zl.z, zl.w, acc);
    acc = fma2i(u.z, zh.x, zh.y, acc);
    acc = fma2i(u.w, zh.z, zh.w, acc);
    return acc;
}
__device__ __forceinline__ int q15(float w, float inv) {
    float q = rintf(w * inv);
    q = fmaxf(-32767.0f, fminf(32767.0f, q));
    return (int)q;
}
__device__ __forceinline__ unsigned pack16(int a, int b) {
    return ((unsigned)a & 0xffffu) | ((unsigned)b << 16);
}

// one wave (64 threads) per row; rows: [0,2112) W2, [2112,2240) W1, [2240,2368) W0
__global__ __launch_bounds__(64)
void prep_kernel(const float* __restrict__ vW0, const float* __restrict__ vW1,
                 const float* __restrict__ vW2, unsigned* __restrict__ ws)
{
    const int row  = blockIdx.x;
    const int lane = threadIdx.x;
    float* scf = (float*)ws;

    if (row < kO) {                                   // vW2 row, 128 cols
        if (row < 4) ws[WS_FLAG + row * 64 + lane] = 0;   // zero exchange flags
        const float* src = vW2 + (size_t)row * kW;
        float m = fmaxf(fabsf(src[lane]), fabsf(src[lane + 64]));
        #pragma unroll
        for (int s = 1; s < 64; s <<= 1) m = fmaxf(m, __shfl_xor(m, s));
        float inv = (m > 0.0f) ? 32767.0f / m : 0.0f;
        if (lane == 0) scf[WS_SC2 + row] = (m > 0.0f) ? m / 32767.0f : 0.0f;
        int w = lane;
        unsigned pk = pack16(q15(src[2 * w], inv), q15(src[2 * w + 1], inv));
        int R = row >> 6, r = row & 63, q = w >> 2, e = w & 3;
        ws[WS_W2 + (((R * 16 + q) * 64 + r) << 2) + e] = pk;
    } else if (row < kO + kW) {                       // vW1 row, 128 cols
        int r = row - kO;
        const float* src = vW1 + (size_t)r * kW;
        float m = fmaxf(fabsf(src[lane]), fabsf(src[lane + 64]));
        #pragma unroll
        for (int s = 1; s < 64; s <<= 1) m = fmaxf(m, __shfl_xor(m, s));
        float inv = (m > 0.0f) ? 32767.0f / m : 0.0f;
        if (lane == 0) scf[WS_SC1 + r] = (m > 0.0f) ? m / 32767.0f : 0.0f;
        int w = lane;
        ws[WS_W1 + r * 64 + w] = pack16(q15(src[2 * w], inv), q15(src[2 * w + 1], inv));
    } else {                                          // vW0 row, 65 cols
        int r = row - kO - kW;
        const float* src = vW0 + (size_t)r * kIN;
        float m = fabsf(src[lane]);
        if (lane == 0) m = fmaxf(m, fabsf(src[64]));
        #pragma unroll
        for (int s = 1; s < 64; s <<= 1) m = fmaxf(m, __shfl_xor(m, s));
        float inv = (m > 0.0f) ? 32767.0f / m : 0.0f;
        if (lane == 0) scf[WS_SC0 + r] = (m > 0.0f) ? m / 32767.0f : 0.0f;
        if (lane < 33) {
            int c0 = 2 * lane, c1 = 2 * lane + 1;
            int qa = q15(src[c0], inv);
            int qb = (c1 < kIN) ? q15(src[c1], inv) : 0;
            ws[WS_W0 + r * 33 + lane] = pack16(qa, qb);
        }
    }
}

// ============================================================================
// SPLIT kernel: 2 blocks per batch. Block role R owns v rows [1056R, 1056R+1056)
// = heads h in [32R, 32R+32). Per step both blocks compute full z1/z2 (cheap,
// duplicated) and half of S3/S4; yhat halves are exchanged via agent-scope
// atomics + monotone flags. All 256 blocks co-resident (16 waves, ~7 KB LDS).
// ============================================================================
__global__ __launch_bounds__(BLOCK)
void cde_split(
    const float* __restrict__ ts,  const float* __restrict__ ys,
    const float* __restrict__ iW0, const float* __restrict__ ib0,
    const float* __restrict__ iW1, const float* __restrict__ ib1,
    const float* __restrict__ iW2, const float* __restrict__ ib2,
    const float* __restrict__ vW0, const float* __restrict__ vb0,
    const float* __restrict__ vW1, const float* __restrict__ vb1,
    const float* __restrict__ vW2, const float* __restrict__ vb2,
    const float* __restrict__ rW,  const float* __restrict__ rb,
    unsigned* wsm,
    float* __restrict__ out)
{
    const int batch = blockIdx.x & 127;
    const int R     = blockIdx.x >> 7;      // role 0 (h 0..31) / 1 (h 32..63)
    const int t  = threadIdx.x;
    const int r8 = t >> 3;
    const int g  = t & 7;

    __shared__ __align__(16) float s_v[1056];        // v rows for own half
    __shared__ __align__(16) float s_z1[kW], s_z2[kW];
    __shared__ __align__(16) float s_inp[kIN + 1];   // full [t, yhat(64)] + pad
    __shared__ float s_y[32], s_yhat[32], s_e[32];   // own half
    __shared__ float s_x[3][34];

    const float*    ysb   = ys + (size_t)batch * kT * kD;
    const unsigned* wsb   = wsm;
    const uint4*    wsW2q = (const uint4*)(wsb + WS_W2);
    const unsigned* wsW1  = wsb + WS_W1;
    const unsigned* wsW0  = wsb + WS_W0;
    const float*    scf   = (const float*)wsb;
    float*    xbf = (float*)(wsm + WS_XB) + (size_t)batch * 128;   // [2][64]
    unsigned* flg = wsm + WS_FLAG + batch * 2;

    // per-thread constants
    const int rowM = R * 1056 + t;                   // S3 main row (t<1024 all valid)
    const float bM = vb2[rowM];
    const float sM = scf[WS_SC2 + rowM];
    const int rowT = R * 1056 + 1024 + (t >> 3);     // S3 tail row (t<256)
    const float bT = (t < 256) ? vb2[rowT] : 0.0f;
    const float sT = (t < 256) ? scf[WS_SC2 + rowT] : 0.0f;
    const float b0r = vb0[r8];
    const float b1r = vb1[r8];
    const float s0r = scf[WS_SC0 + r8];
    const float s1r = scf[WS_SC1 + r8];

    // ---- x staging init ----
    float x_next = 0.0f;
    const float* yptr = nullptr;
    if (t < kC) {
        float x0v, x1v;
        if (t == 0) { x0v = ts[0]; x1v = ts[1]; }
        else {
            const float* p = ysb + (t - 1);
            x0v = p[0]; x1v = p[kD]; yptr = p + 2 * kD;
        }
        s_x[0][t] = x0v; s_x[1][t] = x1v; s_x[2][t] = 0.0f;
        x_next = x1v;
    }
    if (t == 0) s_inp[kIN] = 0.0f;
    __syncthreads();

    // ---- initial MLP (fp32, both blocks compute identically) ----
    if (t < kW) {
        const float* wrow = iW0 + t * kC;
        float acc = ib0[t];
        #pragma unroll
        for (int c = 0; c < kC; c++) acc += wrow[c] * s_x[0][c];
        s_z1[t] = fmaxf(acc, 0.0f);
    }
    __syncthreads();
    if (t < kW) {
        const float4* wr = (const float4*)(iW1 + t * kW);
        const float4* z4 = (const float4*)s_z1;
        float acc = ib1[t];
        #pragma unroll 8
        for (int q = 0; q < kW / 4; q++) acc += dot4(wr[q], z4[q]);
        s_z2[t] = fmaxf(acc, 0.0f);
    }
    __syncthreads();
    if (t < kH) {
        const float4* wr = (const float4*)(iW2 + t * kW);
        const float4* z4 = (const float4*)s_z2;
        float acc = ib2[t];
        #pragma unroll 8
        for (int q = 0; q < kW / 4; q++) acc += dot4(wr[q], z4[q]);
        s_inp[1 + t] = acc;                 // full yhat0 available locally
        if ((t >> 5) == R) {                // own half state
            s_y[t & 31] = acc; s_yhat[t & 31] = acc;
        }
    }
    if (t == 0) s_inp[0] = ts[0];
    __syncthreads();

    const uint4* pW = wsW2q + ((size_t)(rowM >> 6) * 16) * 64 + (rowM & 63);

    // ---- main scan: 5 barriers + exchange per step ----
    for (int i = 0; i < kT; i++) {
        const int i0  = i % 3;
        const int ip1 = (i + 1) % 3;
        const int im1 = (i + 2) % 3;

        // ===== S1: layer1 (65->128), split-k-8 ; x publish/prefetch =====
        {
            float acc = 0.0f;
            const unsigned* rowp = wsW0 + r8 * 33;
            #pragma unroll
            for (int m = 0; m < 5; m++) {
                int p = g + 8 * m;
                if (p < 33) acc = fma2i(rowp[p], s_inp[2 * p], s_inp[2 * p + 1], acc);
            }
            acc += __shfl_xor(acc, 1);
            acc += __shfl_xor(acc, 2);
            acc += __shfl_xor(acc, 4);
            if (g == 0) s_z1[r8] = lipswish_f(b0r + s0r * acc);
        }
        if (t < kC && i + 1 < kT) {
            s_x[ip1][t] = x_next;
            if (i + 2 < kT) {
                if (t == 0) x_next = ts[i + 2];
                else { x_next = *yptr; yptr += kD; }
            }
        }
        __syncthreads();

        // ===== S2: layer2 (128->128), split-k-8 =====
        {
            float acc = 0.0f;
            #pragma unroll
            for (int m = 0; m < 2; m++) {
                int ch = g + 8 * m;
                const float4* z4 = (const float4*)(s_z1 + 8 * ch);
                float4 za = z4[0], zb = z4[1];
                uint4 u = *(const uint4*)(wsW1 + r8 * 64 + 4 * ch);
                acc = fma8i(u, za, zb, acc);
            }
            acc += __shfl_xor(acc, 1);
            acc += __shfl_xor(acc, 2);
            acc += __shfl_xor(acc, 4);
            if (g == 0) s_z2[r8] = lipswish_f(b1r + s1r * acc);
        }
        __syncthreads();

        // ===== S3 main: one row per thread (own half, 1024 rows) =====
        {
            float acc = 0.0f;
            #pragma unroll 2
            for (int m = 0; m < 8; m++) {
                uint4 w0 = pW[(2 * m) * 64], w1 = pW[(2 * m + 1) * 64];
                const float4* z4 = (const float4*)(s_z2 + 16 * m);
                acc = fma8i(w0, z4[0], z4[1], acc);
                acc = fma8i(w1, z4[2], z4[3], acc);
            }
            s_v[t] = fast_tanh(bM + sM * acc);
        }
        // ===== S3 tail: 32 rows, split-k-8 =====
        if (t < 256) {
            const float4* z4 = (const float4*)(s_z2 + 16 * g);
            float4 z0 = z4[0], z1 = z4[1], z2 = z4[2], z3 = z4[3];
            const size_t qb = ((size_t)(rowT >> 6) * 16) * 64 + (rowT & 63);
            uint4 u0 = wsW2q[qb + (size_t)(2 * g) * 64];
            uint4 u1 = wsW2q[qb + (size_t)(2 * g + 1) * 64];
            float acc = fma8i(u0, z0, z1, 0.0f);
            acc = fma8i(u1, z2, z3, acc);
            acc += __shfl_xor(acc, 1);
            acc += __shfl_xor(acc, 2);
            acc += __shfl_xor(acc, 4);
            if (g == 0) s_v[1024 + (t >> 3)] = fast_tanh(bT + sT * acc);
        }
        __syncthreads();

        // ===== S4: own-half einsums + state update; publish yhat half =====
        if (t < 32) {
            const float* vr = s_v + t * kC;
            const float* xm = s_x[im1];
            const float* xc = s_x[i0];
            const float* xp = s_x[ip1];
            float dA = 0.0f, dB = 0.0f;
            #pragma unroll
            for (int c = 0; c < kC; c++) {
                float vv = vr[c];
                dA += vv * (xc[c] - xm[c]);
                dB += vv * (xp[c] - xc[c]);
            }
            if (i > 0) s_y[t] += 0.5f * (s_e[t] + dA);
            if (i < kT - 1) {
                s_e[t] = dB;
                float yh = 2.0f * s_y[t] - s_yhat[t] + dB;
                s_yhat[t] = yh;
                const int hg = R * 32 + t;
                s_inp[1 + hg] = yh;
                __hip_atomic_store(&xbf[(i & 1) * 64 + hg], yh,
                                   __ATOMIC_RELAXED, __HIP_MEMORY_SCOPE_AGENT);
            }
        }
        // exchange (wave 0 only; other waves run to the loop barrier)
        if (i < kT - 1) {
            if (t == 0) {
                s_inp[0] = s_x[ip1][0];
                // drain this wave's data stores, then release the flag
                asm volatile("s_waitcnt vmcnt(0)" ::: "memory");
                __hip_atomic_store(flg + R, (unsigned)(i + 1),
                                   __ATOMIC_RELEASE, __HIP_MEMORY_SCOPE_AGENT);
            }
            if (t < 32) {
                const unsigned tgt = (unsigned)(i + 1);
                while (__hip_atomic_load(flg + (1 - R), __ATOMIC_ACQUIRE,
                                         __HIP_MEMORY_SCOPE_AGENT) < tgt)
                    __builtin_amdgcn_s_sleep(2);
                const int ph = (1 - R) * 32 + t;
                float pv = __hip_atomic_load(&xbf[(i & 1) * 64 + ph],
                                             __ATOMIC_RELAXED, __HIP_MEMORY_SCOPE_AGENT);
                s_inp[1 + ph] = pv;
            }
        }
        __syncthreads();
    }

    // ---- readout: role H publishes partial; role L writes out (idempotent) ----
    if (R == 1) {
        if (t == 0) {
            float ph = 0.0f;
            #pragma unroll
            for (int h = 0; h < 32; h++) ph += s_y[h] * rW[32 + h];
            __hip_atomic_store(&xbf[127], ph, __ATOMIC_RELAXED, __HIP_MEMORY_SCOPE_AGENT);
            asm volatile("s_waitcnt vmcnt(0)" ::: "memory");
            __hip_atomic_store(flg + 1, 1024u, __ATOMIC_RELEASE, __HIP_MEMORY_SCOPE_AGENT);
        }
    } else {
        if (t == 0) {
            float pl = rb[0];
            #pragma unroll
            for (int h = 0; h < 32; h++) pl += s_y[h] * rW[h];
            while (__hip_atomic_load(flg + 1, __ATOMIC_ACQUIRE,
                                     __HIP_MEMORY_SCOPE_AGENT) < 1024u)
                __builtin_amdgcn_s_sleep(2);
            float ph = __hip_atomic_load(&xbf[127], __ATOMIC_RELAXED,
                                         __HIP_MEMORY_SCOPE_AGENT);
            out[batch] = pl + ph;
        }
    }
}

// ============================================================================
// MONO fallback: round-0 proven kernel (6456 us, absmax 4.0), unchanged.
// ============================================================================
template <int QI>
__global__ __launch_bounds__(BLOCK)
void cde_mono(
    const float* __restrict__ ts,  const float* __restrict__ ys,
    const float* __restrict__ iW0, const float* __restrict__ ib0,
    const float* __restrict__ iW1, const float* __restrict__ ib1,
    const float* __restrict__ iW2, const float* __restrict__ ib2,
    const float* __restrict__ vW0, const float* __restrict__ vb0,
    const float* __restrict__ vW1, const float* __restrict__ vb1,
    const float* __restrict__ vW2, const float* __restrict__ vb2,
    const float* __restrict__ rW,  const float* __restrict__ rb,
    const unsigned* __restrict__ wsb,
    float* __restrict__ out)
{
    const int b  = blockIdx.x;
    const int t  = threadIdx.x;
    const int r8 = t >> 3;
    const int g  = t & 7;
    const int wv = t >> 6;
    const int ln = t & 63;

    __shared__ __align__(16) float s_v[kO];
    __shared__ __align__(16) float s_z1[kW], s_z2[kW];
    __shared__ __align__(16) float s_inp[kIN + 1];
    __shared__ float s_y[kH], s_yhat[kH], s_e[kH];
    __shared__ float s_dx[kC];

    const float*    ysb   = ys + (size_t)b * kT * kD;
    const uint4*    wsW2q = (const uint4*)(wsb + WS_W2);
    const unsigned* wsW1  = wsb + WS_W1;
    const unsigned* wsW0  = wsb + WS_W0;
    const float*    scf   = (const float*)wsb;

    const float bA  = vb2[t];
    const float bB  = vb2[t + 1024];
    const float bTl = (t < 512) ? vb2[2048 + r8] : 0.0f;
    const float b0r = vb0[r8];
    const float b1r = vb1[r8];
    const float sA  = QI ? scf[WS_SC2 + t] : 0.0f;
    const float sB  = QI ? scf[WS_SC2 + t + 1024] : 0.0f;
    const float sTl = (QI && t < 512) ? scf[WS_SC2 + 2048 + r8] : 0.0f;
    const float s0r = QI ? scf[WS_SC0 + r8] : 0.0f;
    const float s1r = QI ? scf[WS_SC1 + r8] : 0.0f;

    float x_reg = 0.0f, x_next = 0.0f;
    if (t < kC) {
        x_reg  = (t == 0) ? ts[0] : ysb[t - 1];
        x_next = (t == 0) ? ts[1] : ysb[kD + (t - 1)];
        s_dx[t] = x_reg;
    }
    if (t == 0) s_inp[kIN] = 0.0f;
    __syncthreads();

    if (t < kW) {
        const float* wrow = iW0 + t * kC;
        float acc = ib0[t];
        #pragma unroll
        for (int c = 0; c < kC; c++) acc += wrow[c] * s_dx[c];
        s_z1[t] = fmaxf(acc, 0.0f);
    }
    __syncthreads();
    if (t < kW) {
        const float4* wr = (const float4*)(iW1 + t * kW);
        const float4* z4 = (const float4*)s_z1;
        float acc = ib1[t];
        #pragma unroll 8
        for (int q = 0; q < kW / 4; q++) acc += dot4(wr[q], z4[q]);
        s_z2[t] = fmaxf(acc, 0.0f);
    }
    __syncthreads();
    if (t < kH) {
        const float4* wr = (const float4*)(iW2 + t * kW);
        const float4* z4 = (const float4*)s_z2;
        float acc = ib2[t];
        #pragma unroll 8
        for (int q = 0; q < kW / 4; q++) acc += dot4(wr[q], z4[q]);
        s_y[t] = acc; s_yhat[t] = acc;
        s_inp[1 + t] = acc;
    }
    if (t == 0) s_inp[0] = x_reg;
    __syncthreads();

    for (int i = 0; i < kT; i++) {
        {
            float acc = 0.0f;
            if (QI) {
                const unsigned* rowp = wsW0 + r8 * 33;
                #pragma unroll
                for (int m = 0; m < 5; m++) {
                    int p = g + 8 * m;
                    if (p < 33) acc = fma2i(rowp[p], s_inp[2 * p], s_inp[2 * p + 1], acc);
                }
            } else {
                const float* rowp = vW0 + r8 * kIN;
                #pragma unroll
                for (int m = 0; m < 5; m++) {
                    int p = g + 8 * m;
                    if (p < 33) {
                        float w0 = rowp[2 * p];
                        float w1 = (2 * p + 1 < kIN) ? rowp[2 * p + 1] : 0.0f;
                        acc += w0 * s_inp[2 * p] + w1 * s_inp[2 * p + 1];
                    }
                }
            }
            acc += __shfl_xor(acc, 1);
            acc += __shfl_xor(acc, 2);
            acc += __shfl_xor(acc, 4);
            if (g == 0) s_z1[r8] = lipswish_f(b0r + (QI ? s0r * acc : acc));
        }
        __syncthreads();
        {
            float acc = 0.0f;
            #pragma unroll
            for (int m = 0; m < 2; m++) {
                int ch = g + 8 * m;
                int c0 = 8 * ch;
                const float4* z4 = (const float4*)(s_z1 + c0);
                float4 za = z4[0], zb = z4[1];
                if (QI) {
                    uint4 u = *(const uint4*)(wsW1 + r8 * 64 + 4 * ch);
                    acc = fma8i(u, za, zb, acc);
                } else {
                    const float* wr = vW1 + r8 * kW + c0;
                    acc += dot4(*(const float4*)wr, za) + dot4(*(const float4*)(wr + 4), zb);
                }
            }
            acc += __shfl_xor(acc, 1);
            acc += __shfl_xor(acc, 2);
            acc += __shfl_xor(acc, 4);
            if (g == 0) s_z2[r8] = lipswish_f(b1r + (QI ? s1r * acc : acc));
        }
        __syncthreads();
        {
            float acc0 = 0.0f, acc1 = 0.0f;
            if (QI) {
                const uint4* pA = wsW2q + (size_t)(wv * 16) * 64 + ln;
                const uint4* pB = wsW2q + (size_t)((wv + 16) * 16) * 64 + ln;
                #pragma unroll 2
                for (int m = 0; m < 8; m++) {
                    const float4* z4 = (const float4*)(s_z2 + 16 * m);
                    float4 z0 = z4[0], z1 = z4[1], z2 = z4[2], z3 = z4[3];
                    uint4 a0 = pA[(2 * m) * 64],     a1 = pA[(2 * m + 1) * 64];
                    uint4 c0 = pB[(2 * m) * 64],     c1 = pB[(2 * m + 1) * 64];
                    acc0 = fma8i(a0, z0, z1, acc0);
                    acc0 = fma8i(a1, z2, z3, acc0);
                    acc1 = fma8i(c0, z0, z1, acc1);
                    acc1 = fma8i(c1, z2, z3, acc1);
                }
                s_v[t]        = fast_tanh(bA + sA * acc0);
                s_v[t + 1024] = fast_tanh(bB + sB * acc1);
            } else {
                #pragma unroll 2
                for (int m = 0; m < 8; m++) {
                    const float4* z4 = (const float4*)(s_z2 + 16 * m);
                    float4 z0 = z4[0], z1 = z4[1], z2 = z4[2], z3 = z4[3];
                    const float4* rA = (const float4*)(vW2 + (size_t)t * kW + 16 * m);
                    const float4* rB = (const float4*)(vW2 + (size_t)(t + 1024) * kW + 16 * m);
                    acc0 += dot4(rA[0], z0) + dot4(rA[1], z1) + dot4(rA[2], z2) + dot4(rA[3], z3);
                    acc1 += dot4(rB[0], z0) + dot4(rB[1], z1) + dot4(rB[2], z2) + dot4(rB[3], z3);
                }
                s_v[t]        = fast_tanh(bA + acc0);
                s_v[t + 1024] = fast_tanh(bB + acc1);
            }
        }
        if (t < 512) {
            int c0 = 16 * g;
            const float4* z4 = (const float4*)(s_z2 + c0);
            float4 z0 = z4[0], z1 = z4[1], z2 = z4[2], z3 = z4[3];
            float acc = 0.0f;
            if (QI) {
                uint4 u0 = wsW2q[(size_t)(32 * 16 + 2 * g) * 64 + r8];
                uint4 u1 = wsW2q[(size_t)(32 * 16 + 2 * g + 1) * 64 + r8];
                acc = fma8i(u0, z0, z1, acc);
                acc = fma8i(u1, z2, z3, acc);
            } else {
                const float4* wr = (const float4*)(vW2 + (size_t)(2048 + r8) * kW + c0);
                acc += dot4(wr[0], z0) + dot4(wr[1], z1) + dot4(wr[2], z2) + dot4(wr[3], z3);
            }
            acc += __shfl_xor(acc, 1);
            acc += __shfl_xor(acc, 2);
            acc += __shfl_xor(acc, 4);
            if (g == 0) s_v[2048 + r8] = fast_tanh(bTl + (QI ? sTl * acc : acc));
        }
        __syncthreads();

        if (i > 0 && t < kH) {
            const float* vr = s_v + t * kC;
            float acc = 0.0f;
            #pragma unroll
            for (int c = 0; c < kC; c++) acc += vr[c] * s_dx[c];
            s_y[t] += 0.5f * (s_e[t] + acc);
        }
        __syncthreads();

        if (i < kT - 1) {
            if (t < kC) {
                float xi = x_next;
                s_dx[t] = xi - x_reg;
                x_reg = xi;
                if (i + 2 < kT)
                    x_next = (t == 0) ? ts[i + 2] : ysb[(size_t)(i + 2) * kD + (t - 1)];
            }
            __syncthreads();
            if (t < kH) {
                const float* vr = s_v + t * kC;
                float e = 0.0f;
                #pragma unroll
                for (int c = 0; c < kC; c++) e += vr[c] * s_dx[c];
                s_e[t] = e;
                float yh = 2.0f * s_y[t] - s_yhat[t] + e;
                s_yhat[t] = yh;
                s_inp[1 + t] = yh;
            }
            if (t == 0) s_inp[0] = x_reg;
            __syncthreads();
        }
    }

    __syncthreads();
    if (t == 0) {
        float acc = rb[0];
        #pragma unroll
        for (int h = 0; h < kH; h++) acc += s_y[h] * rW[h];
        out[b] = acc;
    }
}

extern "C" void kernel_launch(void* const* d_in, const int* in_sizes, int n_in,
                              void* d_out, int out_size, void* d_ws, size_t ws_size,
                              hipStream_t stream)
{
    const float* ts  = (const float*)d_in[0];
    const float* ys  = (const float*)d_in[1];
    const float* iW0 = (const float*)d_in[2];
    const float* ib0 = (const float*)d_in[3];
    const float* iW1 = (const float*)d_in[4];
    const float* ib1 = (const float*)d_in[5];
    const float* iW2 = (const float*)d_in[6];
    const float* ib2 = (const float*)d_in[7];
    const float* vW0 = (const float*)d_in[8];
    const float* vb0 = (const float*)d_in[9];
    const float* vW1 = (const float*)d_in[10];
    const float* vb1 = (const float*)d_in[11];
    const float* vW2 = (const float*)d_in[12];
    const float* vb2 = (const float*)d_in[13];
    const float* rW  = (const float*)d_in[14];
    const float* rb  = (const float*)d_in[15];
    float* out = (float*)d_out;
    unsigned* ws = (unsigned*)d_ws;

    if (ws_size >= (size_t)WS_TOT2 * 4) {
        hipLaunchKernelGGL(prep_kernel, dim3(kO + kW + kW), dim3(64), 0, stream,
                           vW0, vW1, vW2, ws);
        hipLaunchKernelGGL(cde_split, dim3(2 * kB), dim3(BLOCK), 0, stream,
                           ts, ys, iW0, ib0, iW1, ib1, iW2, ib2,
                           vW0, vb0, vW1, vb1, vW2, vb2, rW, rb, ws, out);
    } else if (ws_size >= (size_t)WS_TOT * 4) {
        hipLaunchKernelGGL(prep_kernel, dim3(kO + kW + kW), dim3(64), 0, stream,
                           vW0, vW1, vW2, ws);
        hipLaunchKernelGGL((cde_mono<1>), dim3(kB), dim3(BLOCK), 0, stream,
                           ts, ys, iW0, ib0, iW1, ib1, iW2, ib2,
                           vW0, vb0, vW1, vb1, vW2, vb2, rW, rb, ws, out);
    } else {
        hipLaunchKernelGGL((cde_mono<0>), dim3(kB), dim3(BLOCK), 0, stream,
                           ts, ys, iW0, ib0, iW1, ib1, iW2, ib2,
                           vW0, vb0, vW1, vb1, vW2, vb2, rW, rb, ws, out);
    }
}